// Round 6
// baseline (240.008 us; speedup 1.0000x reference)
//
#include <hip/hip_runtime.h>
#include <hip/hip_bf16.h>

// Problem constants (from reference)
#define P_TOTAL 16384      // H*W pixels
#define KN      16         // kernels per pixel
#define CK      144        // in_channel * kernel_size
#define BATCH   8
#define IMG     262144     // C*H*W
#define NP      8          // pixels per block
#define NCHUNK  (P_TOTAL / NP)   // 2048 blocks
#define ROWS    (CK * NP)        // 1152 gather rows per block

// Session ledger:
//  - ~176 us of dur_us is unconditional harness tax (2x 576 MB d_ws poison fills).
//  - R3 nt-loads: NEUTRAL. R4 per-pixel pipeline: NEUTRAL (barrier drains vmcnt(0)
//    every pixel). R5 bf16 LDS patch (read count /2): NEUTRAL.
//  - R6 theory: effective read BW caps at ~3.7 TB/s (R1 hard datapoint) because the
//    loads-outstanding duty cycle is low: every pixel iteration ends in a barrier
//    that drains all VMEM. Fix: ONE barrier per block (gather all 8 pixels at once,
//    ~1152 requests in flight), then a barrier-FREE compute phase where the weight
//    stream is issued 2 pixels ahead with counted (never-drained) vmcnt waits.

__device__ __forceinline__ float blo16(uint32_t u) {
    union { uint32_t i; float f; } v; v.i = u << 16;        return v.f;
}
__device__ __forceinline__ float bhi16(uint32_t u) {
    union { uint32_t i; float f; } v; v.i = u & 0xffff0000u; return v.f;
}

// ---------------- transpose+quantize: x[b][id] (f32) -> xt[id][b] (bf16) ----------------
__global__ __launch_bounds__(256) void transpose_x_bf16(
    const float* __restrict__ x, float4* __restrict__ xt)
{
    const int i = blockIdx.x * 256 + threadIdx.x;   // id in [0, IMG)
    union { __hip_bfloat16 h[8]; float4 f4; } u;
#pragma unroll
    for (int b = 0; b < BATCH; ++b)
        u.h[b] = __float2bfloat16(
            __builtin_nontemporal_load(&x[(size_t)b * IMG + i]));  // read-once stream
    xt[i] = u.f4;
}

// ---------------- main kernel: single-barrier burst structure ----------------
__global__ __launch_bounds__(256) void abc2d_xt_burst(
    const float4* __restrict__ xt,    // bf16x8 [IMG]
    const float*  __restrict__ w,     // [P, KN, CK]
    const int*    __restrict__ hidx,  // [P, CK]
    float* __restrict__ out)          // [B, KN, P]
{
    __shared__ float4 patchv[ROWS];                 // 8 pixels x 144 rows x 16B = 18.4 kB
    __shared__ float  outbuf[KN * BATCH * NP];      // 4 kB staged output

    // XCD swizzle over 2048 chunks (2048 % 8 == 0 -> bijective)
    const int bid   = blockIdx.x;
    const int chunk = (bid & 7) * (NCHUNK / 8) + (bid >> 3);
    const int p0    = chunk * NP;
    const int t     = threadIdx.x;
    const int k     = t >> 4;
    const int cs    = t & 15;

    // ---- weight streams for pixels 0,1 issued FIRST: they complete for free
    //      under phase A's gather latency (and the single barrier's drain) ----
    float wcur[9], wnxt[9], wnx2[9];
    {
        const float* wp0 = w + (size_t)p0 * (KN * CK) + (size_t)k * CK + cs;
#pragma unroll
        for (int i = 0; i < 9; ++i)
            wcur[i] = __builtin_nontemporal_load(wp0 + 16 * i);
        const float* wp1 = wp0 + KN * CK;
#pragma unroll
        for (int i = 0; i < 9; ++i)
            wnxt[i] = __builtin_nontemporal_load(wp1 + 16 * i);
    }

    // ---------------- phase A: gather ALL 8 pixels, ONE barrier ----------------
    // hidx for the block is contiguous (1152 ints) -> fully coalesced.
    // Each thread runs 4-5 independent hidx->xt chains; ~1152 line requests in
    // flight per block maximize memory-level parallelism.
    {
        const int* hp = hidx + (size_t)p0 * CK;
        int ids[4];
#pragma unroll
        for (int u = 0; u < 4; ++u) ids[u] = hp[t + 256 * u];
        int id4 = 0;
        const bool has5 = (t < ROWS - 1024);         // t<128: wave-uniform for waves 2,3
        if (has5) id4 = hp[t + 1024];
#pragma unroll
        for (int u = 0; u < 4; ++u) patchv[t + 256 * u] = xt[ids[u]];
        if (has5) patchv[t + 1024] = xt[id4];
    }
    __syncthreads();   // the ONLY pre-compute barrier in the kernel

    // ---------------- phase B: barrier-free compute, 2-ahead weight stream ----------------
#pragma unroll
    for (int j = 0; j < NP; ++j) {
        // issue pixel j+2's weights; with no barriers these waits are COUNTED
        // vmcnt -> w_{j+1}, w_{j+2} stay in flight through pixel j's compute
        if (j + 2 < NP) {
            const float* wp = w + (size_t)(p0 + j + 2) * (KN * CK) + (size_t)k * CK + cs;
#pragma unroll
            for (int i = 0; i < 9; ++i)
                wnx2[i] = __builtin_nontemporal_load(wp + 16 * i);
        }

        float acc[BATCH];
#pragma unroll
        for (int b = 0; b < BATCH; ++b) acc[b] = 0.f;

        const float4* pj = &patchv[j * CK];
#pragma unroll
        for (int i = 0; i < 9; ++i) {
            const float wv = wcur[i];
            const float4 q = pj[cs + 16 * i];        // b128, 2-way alias = free
            const uint32_t d0 = __float_as_uint(q.x);
            const uint32_t d1 = __float_as_uint(q.y);
            const uint32_t d2 = __float_as_uint(q.z);
            const uint32_t d3 = __float_as_uint(q.w);
            acc[0] += wv * blo16(d0);
            acc[1] += wv * bhi16(d0);
            acc[2] += wv * blo16(d1);
            acc[3] += wv * bhi16(d1);
            acc[4] += wv * blo16(d2);
            acc[5] += wv * bhi16(d2);
            acc[6] += wv * blo16(d3);
            acc[7] += wv * bhi16(d3);
        }

        // reduce across the 16 cs lanes
#pragma unroll
        for (int b = 0; b < BATCH; ++b) {
            float v = acc[b];
            v += __shfl_xor(v, 1);
            v += __shfl_xor(v, 2);
            v += __shfl_xor(v, 4);
            v += __shfl_xor(v, 8);
            acc[b] = v;
        }

        // stage output (per-wave private k rows; no cross-wave hazard)
        if (cs == 0) {
#pragma unroll
            for (int b = 0; b < BATCH; ++b)
                outbuf[(k * BATCH + b) * NP + j] = acc[b];
        }

        // rotate weight registers (fully unrolled -> SSA rename, no v_movs)
#pragma unroll
        for (int i = 0; i < 9; ++i) { wcur[i] = wnxt[i]; wnxt[i] = wnx2[i]; }
    }

    // ---------------- coalesced output flush: 32B per (b,k) row ----------------
    __syncthreads();
    if (t < KN * BATCH) {
        const int kk = t >> 3;
        const int bb = t & 7;
        const float* src = &outbuf[(kk * BATCH + bb) * NP];
        const float4 v0 = *reinterpret_cast<const float4*>(src);
        const float4 v1 = *reinterpret_cast<const float4*>(src + 4);
        float* dst = &out[((size_t)bb * KN + kk) * P_TOTAL + p0];   // p0 8-aligned
        *reinterpret_cast<float4*>(dst)     = v0;
        *reinterpret_cast<float4*>(dst + 4) = v1;
    }
}

// ---------------- fallback: direct f32 gather (no workspace) ----------------
#define PSTRIDE 12
__global__ __launch_bounds__(256) void abc2d_direct(
    const float* __restrict__ x, const float* __restrict__ w,
    const int* __restrict__ hidx, float* __restrict__ out)
{
    __shared__ float patch[CK * PSTRIDE];
    const int bid = blockIdx.x;
    const int p   = (bid & 7) * (P_TOTAL / 8) + (bid >> 3);
    const int t   = threadIdx.x;
    const int k   = t >> 4;
    const int cs  = t & 15;

    if (t < CK) {
        const int id = hidx[p * CK + t];
        float v[BATCH];
#pragma unroll
        for (int b = 0; b < BATCH; ++b) v[b] = x[(size_t)b * IMG + (size_t)id];
        float* pr = &patch[t * PSTRIDE];
        *reinterpret_cast<float4*>(pr)     = make_float4(v[0], v[1], v[2], v[3]);
        *reinterpret_cast<float4*>(pr + 4) = make_float4(v[4], v[5], v[6], v[7]);
    }

    const float* wp = w + (size_t)p * (KN * CK) + (size_t)k * CK;
    float wreg[9];
#pragma unroll
    for (int i = 0; i < 9; ++i) wreg[i] = wp[cs + 16 * i];
    __syncthreads();

    float acc[BATCH];
#pragma unroll
    for (int b = 0; b < BATCH; ++b) acc[b] = 0.f;
#pragma unroll
    for (int i = 0; i < 9; ++i) {
        const float wv = wreg[i];
        const float* pr = &patch[(cs + 16 * i) * PSTRIDE];
        const float4 q0 = *reinterpret_cast<const float4*>(pr);
        const float4 q1 = *reinterpret_cast<const float4*>(pr + 4);
        acc[0] += wv * q0.x; acc[1] += wv * q0.y; acc[2] += wv * q0.z; acc[3] += wv * q0.w;
        acc[4] += wv * q1.x; acc[5] += wv * q1.y; acc[6] += wv * q1.z; acc[7] += wv * q1.w;
    }
#pragma unroll
    for (int b = 0; b < BATCH; ++b) {
        float v = acc[b];
        v += __shfl_xor(v, 1); v += __shfl_xor(v, 2);
        v += __shfl_xor(v, 4); v += __shfl_xor(v, 8);
        acc[b] = v;
    }
    if (cs == 0) {
#pragma unroll
        for (int b = 0; b < BATCH; ++b)
            out[(size_t)b * (KN * P_TOTAL) + (size_t)k * P_TOTAL + p] = acc[b];
    }
}

extern "C" void kernel_launch(void* const* d_in, const int* in_sizes, int n_in,
                              void* d_out, int out_size, void* d_ws, size_t ws_size,
                              hipStream_t stream) {
    const float* x    = (const float*)d_in[0];   // [8,16,128,128] f32
    const float* wts  = (const float*)d_in[1];   // [16384,16,144] f32
    const int*   hidx = (const int*)d_in[2];     // [16384,144] int32
    float* out = (float*)d_out;                  // [8,16,16384] f32

    const size_t xt_bytes = (size_t)IMG * BATCH * sizeof(__hip_bfloat16);  // 4.19 MB
    if (ws_size >= xt_bytes) {
        float4* xt = (float4*)d_ws;
        transpose_x_bf16<<<IMG / 256, 256, 0, stream>>>(x, xt);
        abc2d_xt_burst<<<NCHUNK, 256, 0, stream>>>(xt, wts, hidx, out);
    } else {
        abc2d_direct<<<P_TOTAL, 256, 0, stream>>>(x, wts, hidx, out);
    }
}